// Round 5
// baseline (5503.593 us; speedup 1.0000x reference)
//
#include <hip/hip_runtime.h>
#include <math.h>

typedef unsigned short u16;
typedef unsigned int u32;

// ---------------- fp32 transpose: src[R][C] -> dst[C][R], 64x64 tiles ----------------
__global__ __launch_bounds__(256) void k_transp32(const float* __restrict__ src,
                                                  float* __restrict__ dst, int R, int C) {
  __shared__ float tile[64 * 65];
  int ct = C >> 6;
  int r0 = (blockIdx.x / ct) << 6;
  int c0 = (blockIdx.x % ct) << 6;
  int tid = threadIdx.x;
  int rr = tid >> 4, cc = (tid & 15) << 2;
#pragma unroll
  for (int i = 0; i < 4; i++) {
    int r = (i << 4) + rr;
    float4 v = *(const float4*)(src + (size_t)(r0 + r) * C + c0 + cc);
    tile[r * 65 + cc + 0] = v.x; tile[r * 65 + cc + 1] = v.y;
    tile[r * 65 + cc + 2] = v.z; tile[r * 65 + cc + 3] = v.w;
  }
  __syncthreads();
#pragma unroll
  for (int i = 0; i < 4; i++) {
    int rd = (i << 4) + rr;
    float4 o;
    o.x = tile[(cc + 0) * 65 + rd]; o.y = tile[(cc + 1) * 65 + rd];
    o.z = tile[(cc + 2) * 65 + rd]; o.w = tile[(cc + 3) * 65 + rd];
    *(float4*)(dst + (size_t)(c0 + rd) * R + r0 + cc) = o;
  }
}

// ------- conv (fp32): U[b,n,d] = x[b,n,d] + (sum_{m<=n} w[n-m] x[b,m,d]) * rsqrt(n+1) -------
__global__ __launch_bounds__(256) void k_conv32f(const float* __restrict__ x,
                                                 const float* __restrict__ w,
                                                 float* __restrict__ U) {
  __shared__ float As[16 * 68];   // As[k][r] = w[(n0+r)-(m0+k)]
  __shared__ float Bs[16 * 68];   // Bs[k][d] = x[b, m0+k, d0+d]
  int bid = blockIdx.x;
  int b = bid >> 10; int rem = bid & 1023;
  int nt = rem >> 4; int dt = rem & 15;
  int n0 = nt << 6, d0 = dt << 6;
  int tid = threadIdx.x;
  int ty = tid >> 4, tx = tid & 15;
  float acc[4][4] = {};
  int kIters = (nt << 2) + 4;     // m in [0, n0+64)
  for (int it = 0; it < kIters; ++it) {
    int m0 = it << 4;
#pragma unroll
    for (int l = 0; l < 4; l++) {
      int p = (l << 8) + tid;
      { int r = p >> 4, k = p & 15;
        int wi = (n0 + r) - (m0 + k);
        As[k * 68 + r] = (wi >= 0 && wi < 4096) ? w[wi] : 0.0f; }
      { int d = p & 63, k = p >> 6;
        Bs[k * 68 + d] = x[((size_t)(b * 4096 + m0 + k)) * 1024 + d0 + d]; }
    }
    __syncthreads();
#pragma unroll
    for (int k = 0; k < 16; k++) {
      float4 av = *(const float4*)(As + k * 68 + (ty << 2));
      float4 bv = *(const float4*)(Bs + k * 68 + (tx << 2));
      float aa[4] = {av.x, av.y, av.z, av.w};
      float bb[4] = {bv.x, bv.y, bv.z, bv.w};
#pragma unroll
      for (int ii = 0; ii < 4; ii++)
#pragma unroll
        for (int jj = 0; jj < 4; jj++)
          acc[ii][jj] += aa[ii] * bb[jj];
    }
    __syncthreads();
  }
#pragma unroll
  for (int ii = 0; ii < 4; ii++) {
    int n = n0 + (ty << 2) + ii;
    float scale = rsqrtf((float)(n + 1));
#pragma unroll
    for (int jj = 0; jj < 4; jj++) {
      int d = d0 + (tx << 2) + jj;
      size_t idx = ((size_t)(b * 4096 + n)) * 1024 + d;
      U[idx] = x[idx] + acc[ii][jj] * scale;
    }
  }
}

// ---------------- block reduction over 256 threads (4 waves) ----------------
__device__ __forceinline__ float blk_sum(float v, float* sb, int tid) {
#pragma unroll
  for (int off = 32; off > 0; off >>= 1) v += __shfl_down(v, off, 64);
  int wid = tid >> 6;
  if ((tid & 63) == 0) sb[wid] = v;
  __syncthreads();
  if (tid == 0) sb[4] = sb[0] + sb[1] + sb[2] + sb[3];
  __syncthreads();
  return sb[4];
}

// ---------------- LN1: X1 = LN(U; g,b) (fp32 out) ----------------
__global__ __launch_bounds__(256) void k_ln1f(const float* __restrict__ U,
                                              const float* __restrict__ g,
                                              const float* __restrict__ bt,
                                              float* __restrict__ X1) {
  __shared__ float sb[8];
  int row = blockIdx.x; int tid = threadIdx.x;
  int c = tid << 2;
  float4 v = *(const float4*)(U + (size_t)row * 1024 + c);
  float mu = blk_sum(v.x + v.y + v.z + v.w, sb, tid) * (1.0f / 1024.0f);
  float dx = v.x - mu, dy = v.y - mu, dz = v.z - mu, dw = v.w - mu;
  float var = blk_sum(dx * dx + dy * dy + dz * dz + dw * dw, sb, tid) * (1.0f / 1024.0f);
  float rs = 1.0f / sqrtf(var + 1e-5f);
  float4 gv = *(const float4*)(g + c);
  float4 bv = *(const float4*)(bt + c);
  float4 o;
  o.x = dx * rs * gv.x + bv.x;
  o.y = dy * rs * gv.y + bv.y;
  o.z = dz * rs * gv.z + bv.z;
  o.w = dw * rs * gv.w + bv.w;
  *(float4*)(X1 + (size_t)row * 1024 + c) = o;
}

// ------- FFN1 (fp32): Hc = gelu(X1 @ w1^T + b1), chunk (e,bb), W1T[k][f] = w1[f][k] -------
__global__ __launch_bounds__(256) void k_ffn1f(const float* __restrict__ X1,
                                               const float* __restrict__ W1T,
                                               const float* __restrict__ b1,
                                               float* __restrict__ Hc, int e, int bb) {
  __shared__ float As[16 * 68];
  __shared__ float Bs[16 * 68];
  int bid = blockIdx.x;
  int mt = bid >> 6; int ft = bid & 63;
  size_t row0 = (size_t)bb * 4096 + (size_t)e * 2048 + (size_t)mt * 64;
  int f0 = ft << 6;
  int tid = threadIdx.x;
  int ty = tid >> 4, tx = tid & 15;
  float acc[4][4] = {};
  for (int it = 0; it < 64; ++it) {
    int k0 = it << 4;
#pragma unroll
    for (int l = 0; l < 4; l++) {
      int p = (l << 8) + tid;
      { int r = p >> 4, k = p & 15;
        As[k * 68 + r] = X1[(row0 + r) * 1024 + k0 + k]; }
      { int f = p & 63, k = p >> 6;
        Bs[k * 68 + f] = W1T[(size_t)(k0 + k) * 4096 + f0 + f]; }
    }
    __syncthreads();
#pragma unroll
    for (int k = 0; k < 16; k++) {
      float4 av = *(const float4*)(As + k * 68 + (ty << 2));
      float4 bv = *(const float4*)(Bs + k * 68 + (tx << 2));
      float aa[4] = {av.x, av.y, av.z, av.w};
      float bb2[4] = {bv.x, bv.y, bv.z, bv.w};
#pragma unroll
      for (int ii = 0; ii < 4; ii++)
#pragma unroll
        for (int jj = 0; jj < 4; jj++)
          acc[ii][jj] += aa[ii] * bb2[jj];
    }
    __syncthreads();
  }
#pragma unroll
  for (int ii = 0; ii < 4; ii++) {
    int lr = (mt << 6) + (ty << 2) + ii;
#pragma unroll
    for (int jj = 0; jj < 4; jj++) {
      int fg = f0 + (tx << 2) + jj;
      float vv = acc[ii][jj] + b1[fg];
      float ge = 0.5f * vv * (1.0f + erff(vv * 0.70710678118654752f));
      Hc[(size_t)lr * 4096 + fg] = ge;
    }
  }
}

// ------- FFN2 (fp32): Y = Hc @ w2^T, chunk (e,bb), W2T[k][d] = w2[d][k] -------
__global__ __launch_bounds__(256) void k_ffn2f(const float* __restrict__ Hc,
                                               const float* __restrict__ W2T,
                                               float* __restrict__ Y, int e, int bb) {
  __shared__ float As[16 * 68];
  __shared__ float Bs[16 * 68];
  int bid = blockIdx.x;
  int mt = bid >> 4; int dt = bid & 15;
  size_t row0 = (size_t)bb * 4096 + (size_t)e * 2048 + (size_t)mt * 64;
  int d0 = dt << 6;
  int tid = threadIdx.x;
  int ty = tid >> 4, tx = tid & 15;
  float acc[4][4] = {};
  for (int it = 0; it < 256; ++it) {
    int k0 = it << 4;
#pragma unroll
    for (int l = 0; l < 4; l++) {
      int p = (l << 8) + tid;
      { int r = p >> 4, k = p & 15;
        As[k * 68 + r] = Hc[(size_t)((mt << 6) + r) * 4096 + k0 + k]; }
      { int d = p & 63, k = p >> 6;
        Bs[k * 68 + d] = W2T[(size_t)(k0 + k) * 1024 + d0 + d]; }
    }
    __syncthreads();
#pragma unroll
    for (int k = 0; k < 16; k++) {
      float4 av = *(const float4*)(As + k * 68 + (ty << 2));
      float4 bv = *(const float4*)(Bs + k * 68 + (tx << 2));
      float aa[4] = {av.x, av.y, av.z, av.w};
      float bb2[4] = {bv.x, bv.y, bv.z, bv.w};
#pragma unroll
      for (int ii = 0; ii < 4; ii++)
#pragma unroll
        for (int jj = 0; jj < 4; jj++)
          acc[ii][jj] += aa[ii] * bb2[jj];
    }
    __syncthreads();
  }
#pragma unroll
  for (int ii = 0; ii < 4; ii++) {
    size_t gr = row0 + (ty << 2) + ii;
#pragma unroll
    for (int jj = 0; jj < 4; jj++)
      Y[gr * 1024 + d0 + (tx << 2) + jj] = acc[ii][jj];
  }
}

// ------- LN2: out = LN(X1 + s*(Y + b2); lng,lnb) -- FP32 OUTPUT (the fix) -------
__global__ __launch_bounds__(256) void k_ln2f(const float* __restrict__ Y,
                                              const float* __restrict__ X1,
                                              const float* __restrict__ b2a, const float* __restrict__ b2b,
                                              const float* __restrict__ sa, const float* __restrict__ sbp,
                                              const float* __restrict__ ga, const float* __restrict__ gb,
                                              const float* __restrict__ ba, const float* __restrict__ bbp,
                                              float* __restrict__ out) {
  __shared__ float sb[8];
  int row = blockIdx.x; int tid = threadIdx.x;
  int n = row & 4095; int e = n >> 11;
  const float* b2 = e ? b2b : b2a;
  const float* lg = e ? gb : ga;
  const float* lb = e ? bbp : ba;
  float s = e ? sbp[0] : sa[0];
  int c = tid << 2;
  float4 yv = *(const float4*)(Y + (size_t)row * 1024 + c);
  float4 xv = *(const float4*)(X1 + (size_t)row * 1024 + c);
  float4 b2v = *(const float4*)(b2 + c);
  float t0 = xv.x + s * (yv.x + b2v.x);
  float t1 = xv.y + s * (yv.y + b2v.y);
  float t2 = xv.z + s * (yv.z + b2v.z);
  float t3 = xv.w + s * (yv.w + b2v.w);
  float mu = blk_sum(t0 + t1 + t2 + t3, sb, tid) * (1.0f / 1024.0f);
  float d0 = t0 - mu, d1 = t1 - mu, d2 = t2 - mu, d3 = t3 - mu;
  float var = blk_sum(d0 * d0 + d1 * d1 + d2 * d2 + d3 * d3, sb, tid) * (1.0f / 1024.0f);
  float rs = 1.0f / sqrtf(var + 1e-5f);
  float4 gv = *(const float4*)(lg + c);
  float4 bv = *(const float4*)(lb + c);
  float4 o;
  o.x = d0 * rs * gv.x + bv.x;
  o.y = d1 * rs * gv.y + bv.y;
  o.z = d2 * rs * gv.z + bv.z;
  o.w = d3 * rs * gv.w + bv.w;
  *(float4*)(out + (size_t)row * 1024 + c) = o;
}

extern "C" void kernel_launch(void* const* d_in, const int* in_sizes, int n_in,
                              void* d_out, int out_size, void* d_ws, size_t ws_size,
                              hipStream_t stream) {
  (void)out_size; (void)ws_size;
  static const int SIG[18] = {16777216, 4096, 1024, 1024,
                              4194304, 4096, 4194304, 1024, 1, 1024, 1024,
                              4194304, 4096, 4194304, 1024, 1, 1024, 1024};
  const void* P[18];
  bool exact = (n_in >= 18);
  if (exact) {
    for (int i = 0; i < 18; i++) {
      if (in_sizes[i] != SIG[i]) { exact = false; break; }
    }
  }
  if (exact) {
    for (int i = 0; i < 18; i++) P[i] = d_in[i];
  } else {
    bool used[64] = {false};
    int cap = (n_in < 64) ? n_in : 64;
    for (int r = 0; r < 18; r++) {
      int found = -1;
      for (int j = 0; j < cap; j++) {
        if (!used[j] && in_sizes[j] == SIG[r]) { found = j; break; }
      }
      if (found >= 0) { used[found] = true; P[r] = d_in[found]; }
      else            { P[r] = d_in[(r < n_in) ? r : 0]; }
    }
  }
  const float* x     = (const float*)P[0];
  const float* wv    = (const float*)P[1];
  const float* ng    = (const float*)P[2];
  const float* nb    = (const float*)P[3];
  const float* w1_0  = (const float*)P[4];
  const float* b1_0  = (const float*)P[5];
  const float* w2_0  = (const float*)P[6];
  const float* b2_0  = (const float*)P[7];
  const float* s_0   = (const float*)P[8];
  const float* lng_0 = (const float*)P[9];
  const float* lnb_0 = (const float*)P[10];
  const float* w1_1  = (const float*)P[11];
  const float* b1_1  = (const float*)P[12];
  const float* w2_1  = (const float*)P[13];
  const float* b2_1  = (const float*)P[14];
  const float* s_1   = (const float*)P[15];
  const float* lng_1 = (const float*)P[16];
  const float* lnb_1 = (const float*)P[17];

  char* ws = (char*)d_ws;
  float* W1Ta = (float*)(ws + 0);           // 16777216 B  [1024][4096]
  float* W1Tb = (float*)(ws + 16777216);    // 16777216 B
  float* W2Ta = (float*)(ws + 33554432);    // 16777216 B  [4096][1024]
  float* W2Tb = (float*)(ws + 50331648);    // 16777216 B
  float* U    = (float*)(ws + 67108864);    // 67108864 B  (reused as Y)
  float* X1   = (float*)(ws + 134217728);   // 67108864 B
  float* Hc   = (float*)(ws + 201326592);   // 33554432 B  -> ends 234881024
  float* Y    = U;

  k_transp32<<<1024, 256, 0, stream>>>(w1_0, W1Ta, 4096, 1024);
  k_transp32<<<1024, 256, 0, stream>>>(w1_1, W1Tb, 4096, 1024);
  k_transp32<<<1024, 256, 0, stream>>>(w2_0, W2Ta, 1024, 4096);
  k_transp32<<<1024, 256, 0, stream>>>(w2_1, W2Tb, 1024, 4096);
  k_conv32f<<<4096, 256, 0, stream>>>(x, wv, U);
  k_ln1f<<<16384, 256, 0, stream>>>(U, ng, nb, X1);
  for (int e = 0; e < 2; e++) {
    for (int bb = 0; bb < 4; bb++) {
      k_ffn1f<<<2048, 256, 0, stream>>>(X1, e ? W1Tb : W1Ta, e ? b1_1 : b1_0, Hc, e, bb);
      k_ffn2f<<<512, 256, 0, stream>>>(Hc, e ? W2Tb : W2Ta, Y, e, bb);
    }
  }
  k_ln2f<<<16384, 256, 0, stream>>>(Y, X1, b2_0, b2_1, s_0, s_1,
                                    lng_0, lng_1, lnb_0, lnb_1, (float*)d_out);
}